// Round 1
// baseline (6242.015 us; speedup 1.0000x reference)
//
#include <hip/hip_runtime.h>

typedef _Float16 half8 __attribute__((ext_vector_type(8)));
typedef float f32x4 __attribute__((ext_vector_type(4)));

#define NBLK 256
#define NTHR 256
#define VD   512
#define HM   1024
#define MPAD 144
#define BSENT 129

// ---------------- workspace layout ----------------
static constexpr size_t SZ_SWIH = (size_t)4096 * 512 * 2;
static constexpr size_t SZ_W1K  = (size_t)4096 * 1024 * 2;
static constexpr size_t OFF_SWIH = 0;
static constexpr size_t OFF_SWHH = OFF_SWIH + SZ_SWIH;
static constexpr size_t OFF_PWIH = OFF_SWHH + SZ_W1K;
static constexpr size_t OFF_PWHH = OFF_PWIH + SZ_W1K;
static constexpr size_t OFF_BWIH = OFF_PWHH + SZ_W1K;
static constexpr size_t OFF_BWHH = OFF_BWIH + SZ_W1K;
static constexpr size_t OFF_SB   = OFF_BWHH + SZ_W1K;
static constexpr size_t OFF_PB   = OFF_SB + (size_t)4096 * 4;
static constexpr size_t OFF_BB   = OFF_PB + (size_t)4096 * 4;
static constexpr size_t OFF_X16  = OFF_BB + (size_t)4096 * 4;
static constexpr size_t SZ_X16   = (size_t)64 * MPAD * VD * 2;
static constexpr size_t OFF_STATE = OFF_X16 + SZ_X16;
static constexpr size_t OFF_H    = OFF_STATE;                 // [2][144][1024] f16
static constexpr size_t SZ_H     = (size_t)2 * MPAD * HM * 2;
static constexpr size_t OFF_C32  = OFF_H + SZ_H;              // [144][1024] f32
static constexpr size_t SZ_C32   = (size_t)MPAD * HM * 4;
static constexpr size_t OFF_HP   = OFF_C32 + SZ_C32;          // [2][16][1024] f16
static constexpr size_t SZ_HP    = (size_t)2 * 16 * HM * 2;
static constexpr size_t OFF_CP   = OFF_HP + SZ_HP;            // [8][1024] f32
static constexpr size_t SZ_CP    = (size_t)8 * HM * 4;
static constexpr size_t OFF_HB   = OFF_CP + SZ_CP;            // [2][1024] f16
static constexpr size_t SZ_HB    = (size_t)2 * HM * 2;
static constexpr size_t OFF_CB   = OFF_HB + SZ_HB;            // [1024] f32
static constexpr size_t OFF_RH   = OFF_CB + (size_t)HM * 4;   // [1024] f32 r_hidden
static constexpr size_t OFF_BAR  = OFF_RH + (size_t)HM * 4;   // barrier cnt/gen
static constexpr size_t STATE_BYTES = OFF_BAR + 256 - OFF_STATE;

// ---------------- helpers ----------------
__device__ __forceinline__ half8 h8z() {
    half8 z = {(_Float16)0,(_Float16)0,(_Float16)0,(_Float16)0,
               (_Float16)0,(_Float16)0,(_Float16)0,(_Float16)0};
    return z;
}

__device__ __forceinline__ void lstm_cell(float ip, float fp, float gp, float op,
                                          float& c, float& h) {
    float ig = 1.0f / (1.0f + expf(-ip));
    float fg = 1.0f / (1.0f + expf(-fp));
    float og = 1.0f / (1.0f + expf(-op));
    float gv = tanhf(gp);
    c = fg * c + ig * gv;
    h = og * tanhf(c);
}

// sense-reversing grid barrier (agent scope), bar[0]=cnt bar[1]=gen
__device__ __forceinline__ void gsync(unsigned* bar) {
    __threadfence();
    __syncthreads();
    if (threadIdx.x == 0) {
        unsigned g = __hip_atomic_load(&bar[1], __ATOMIC_RELAXED, __HIP_MEMORY_SCOPE_AGENT);
        unsigned a = __hip_atomic_fetch_add(&bar[0], 1u, __ATOMIC_ACQ_REL, __HIP_MEMORY_SCOPE_AGENT);
        if (a == (unsigned)(gridDim.x - 1)) {
            __hip_atomic_store(&bar[0], 0u, __ATOMIC_RELAXED, __HIP_MEMORY_SCOPE_AGENT);
            __hip_atomic_store(&bar[1], g + 1u, __ATOMIC_RELEASE, __HIP_MEMORY_SCOPE_AGENT);
        } else {
            while (__hip_atomic_load(&bar[1], __ATOMIC_RELAXED, __HIP_MEMORY_SCOPE_AGENT) == g) {
                __builtin_amdgcn_s_sleep(2);
            }
        }
    }
    __syncthreads();
    __threadfence();
}

// ---------------- prep kernels ----------------
__global__ void k_cvt(const float* __restrict__ s, _Float16* __restrict__ d, int n) {
    for (int i = blockIdx.x * blockDim.x + threadIdx.x; i < n; i += gridDim.x * blockDim.x)
        d[i] = (_Float16)s[i];
}

__global__ void k_bias(const float* a1, const float* a2, const float* b1, const float* b2,
                       const float* c1, const float* c2,
                       float* sb, float* pb, float* bb) {
    int i = blockIdx.x * blockDim.x + threadIdx.x;
    if (i < 4096) {
        sb[i] = a1[i] + a2[i];
        pb[i] = b1[i] + b2[i];
        bb[i] = c1[i] + c2[i];
    }
}

// X16[t][row][d], t-major; row 0 = headline, rows 1..128 = body sents, 129..143 = zero pad
__global__ void k_gather(const int* __restrict__ head, const int* __restrict__ body,
                         const float* __restrict__ emb, _Float16* __restrict__ X16) {
    const int total = 64 * MPAD * VD;
    for (int idx = blockIdx.x * blockDim.x + threadIdx.x; idx < total;
         idx += gridDim.x * blockDim.x) {
        int d   = idx & (VD - 1);
        int rt  = idx >> 9;
        int row = rt % MPAD;
        int t   = rt / MPAD;
        float v = 0.0f;
        if (row == 0)        v = emb[(size_t)head[t] * VD + d];
        else if (row < BSENT) v = emb[(size_t)body[(row - 1) * 64 + t] * VD + d];
        X16[idx] = (_Float16)v;
    }
}

// ---------------- main persistent kernel ----------------
extern "C" __global__ void __launch_bounds__(NTHR)
k_main(const _Float16* __restrict__ sWih, const _Float16* __restrict__ sWhh,
       const _Float16* __restrict__ pWih, const _Float16* __restrict__ pWhh,
       const _Float16* __restrict__ bWih, const _Float16* __restrict__ bWhh,
       const float* __restrict__ sb, const float* __restrict__ pb, const float* __restrict__ bb,
       const _Float16* __restrict__ X16,
       _Float16* H, float* c32, _Float16* HP, float* cp32, _Float16* HB, float* cb32,
       float* rhid, float* out, unsigned* bar)
{
    __shared__ float lds[4][16][17];

    const int tid  = threadIdx.x;
    const int lane = tid & 63;
    const int wv   = tid >> 6;        // 0..3
    const int l15  = lane & 15;       // MFMA row/col within tile
    const int krow = lane >> 4;       // 0..3 (k-chunk)
    const int rr   = lane >> 2;       // epilogue row 0..15
    const int mm   = lane & 3;        // epilogue unit offset 0..3
    const int ubase = blockIdx.x * 4;                 // 4 hidden units per block
    const int uo    = ubase + mm;
    const int grow  = (l15 >> 2) * 1024 + ubase + (l15 & 3);  // gate-matrix row for B col l15

    const float sbi = sb[uo], sbf = sb[1024 + uo], sbg = sb[2048 + uo], sbo = sb[3072 + uo];
    const float pbi = pb[uo], pbf = pb[1024 + uo], pbg = pb[2048 + uo], pbo = pb[3072 + uo];
    const float bbi = bb[uo], bbf = bb[1024 + uo], bbg = bb[2048 + uo], bbo = bb[3072 + uo];

    // ================= sentence LSTM: 64 steps, batch 129 (pad 144) =================
#pragma unroll 1
    for (int t = 0; t < 64; ++t) {
        const _Float16* Xt = X16 + (size_t)t * MPAD * VD;
        const _Float16* Hr = H + (size_t)(t & 1) * MPAD * HM;
        _Float16*       Hw = H + (size_t)((t + 1) & 1) * MPAD * HM;

        f32x4 a0 = {0.f,0.f,0.f,0.f}, a1 = {0.f,0.f,0.f,0.f}, a2 = {0.f,0.f,0.f,0.f};
        const int r0 = wv * 16 + l15;          // tile wv
        // --- x part (K 0..511) ---
#pragma unroll 4
        for (int kt = 0; kt < 16; ++kt) {
            const int kk = kt * 32 + krow * 8;
            half8 b  = *reinterpret_cast<const half8*>(sWih + (size_t)grow * VD + kk);
            half8 x0 = *reinterpret_cast<const half8*>(Xt + (size_t)r0 * VD + kk);
            half8 x1 = *reinterpret_cast<const half8*>(Xt + (size_t)(r0 + 64) * VD + kk);
            a0 = __builtin_amdgcn_mfma_f32_16x16x32_f16(x0, b, a0, 0, 0, 0);
            a1 = __builtin_amdgcn_mfma_f32_16x16x32_f16(x1, b, a1, 0, 0, 0);
            if (wv == 0) {
                half8 x2 = *reinterpret_cast<const half8*>(Xt + (size_t)(r0 + 128) * VD + kk);
                a2 = __builtin_amdgcn_mfma_f32_16x16x32_f16(x2, b, a2, 0, 0, 0);
            }
        }
        // --- h part (K 512..1535) ---
#pragma unroll 4
        for (int kt = 0; kt < 32; ++kt) {
            const int kk = kt * 32 + krow * 8;
            half8 b  = *reinterpret_cast<const half8*>(sWhh + (size_t)grow * HM + kk);
            half8 h0 = *reinterpret_cast<const half8*>(Hr + (size_t)r0 * HM + kk);
            half8 h1 = *reinterpret_cast<const half8*>(Hr + (size_t)(r0 + 64) * HM + kk);
            a0 = __builtin_amdgcn_mfma_f32_16x16x32_f16(h0, b, a0, 0, 0, 0);
            a1 = __builtin_amdgcn_mfma_f32_16x16x32_f16(h1, b, a1, 0, 0, 0);
            if (wv == 0) {
                half8 h2 = *reinterpret_cast<const half8*>(Hr + (size_t)(r0 + 128) * HM + kk);
                a2 = __builtin_amdgcn_mfma_f32_16x16x32_f16(h2, b, a2, 0, 0, 0);
            }
        }
        // --- fused epilogue per tile (per-wave LDS buffer, no cross-wave sync) ---
        auto epi = [&](const f32x4 acc, int T) {
            lds[wv][krow * 4 + 0][l15] = acc[0];
            lds[wv][krow * 4 + 1][l15] = acc[1];
            lds[wv][krow * 4 + 2][l15] = acc[2];
            lds[wv][krow * 4 + 3][l15] = acc[3];
            asm volatile("s_waitcnt lgkmcnt(0)" ::: "memory");
            const int rowg = T * 16 + rr;
            if (rowg < BSENT) {
                float ip = lds[wv][rr][0 + mm]  + sbi;
                float fp = lds[wv][rr][4 + mm]  + sbf;
                float gp = lds[wv][rr][8 + mm]  + sbg;
                float op = lds[wv][rr][12 + mm] + sbo;
                const size_t o = (size_t)rowg * HM + uo;
                float c = c32[o], h;
                lstm_cell(ip, fp, gp, op, c, h);
                c32[o] = c;
                Hw[o]  = (_Float16)h;
                if (t == 63 && rowg == 0) rhid[uo] = h;
            }
        };
        epi(a0, wv);
        epi(a1, wv + 4);
        if (wv == 0) epi(a2, 8);
        gsync(bar);
    }

    // ================= paragraph LSTM: 16 steps, batch 8 (pad 16) =================
    const _Float16* Hs = H;   // final sentence h landed in buffer 0
#pragma unroll 1
    for (int s = 0; s < 16; ++s) {
        const _Float16* HPr = HP + (size_t)(s & 1) * 16 * HM;
        _Float16*       HPw = HP + (size_t)((s + 1) & 1) * 16 * HM;
        f32x4 acc = {0.f,0.f,0.f,0.f};
        const int rsent = 1 + l15 * 16 + s;    // sent_h[p=l15][s]
#pragma unroll 4
        for (int k = 0; k < 16; ++k) {
            const int kt = wv * 16 + k;        // wave-split K: 64 k-tiles total
            const int kk = kt * 32 + krow * 8;
            half8 b, a = h8z();
            if (kk < 1024) {
                b = *reinterpret_cast<const half8*>(pWih + (size_t)grow * HM + kk);
                if (l15 < 8) a = *reinterpret_cast<const half8*>(Hs + (size_t)rsent * HM + kk);
            } else {
                b = *reinterpret_cast<const half8*>(pWhh + (size_t)grow * HM + (kk - 1024));
                if (l15 < 8) a = *reinterpret_cast<const half8*>(HPr + (size_t)l15 * HM + (kk - 1024));
            }
            acc = __builtin_amdgcn_mfma_f32_16x16x32_f16(a, b, acc, 0, 0, 0);
        }
        lds[wv][krow * 4 + 0][l15] = acc[0];
        lds[wv][krow * 4 + 1][l15] = acc[1];
        lds[wv][krow * 4 + 2][l15] = acc[2];
        lds[wv][krow * 4 + 3][l15] = acc[3];
        __syncthreads();
        if (wv == 0 && rr < 8) {
            float ip = lds[0][rr][0+mm]+lds[1][rr][0+mm]+lds[2][rr][0+mm]+lds[3][rr][0+mm] + pbi;
            float fp = lds[0][rr][4+mm]+lds[1][rr][4+mm]+lds[2][rr][4+mm]+lds[3][rr][4+mm] + pbf;
            float gp = lds[0][rr][8+mm]+lds[1][rr][8+mm]+lds[2][rr][8+mm]+lds[3][rr][8+mm] + pbg;
            float op = lds[0][rr][12+mm]+lds[1][rr][12+mm]+lds[2][rr][12+mm]+lds[3][rr][12+mm] + pbo;
            const size_t o = (size_t)rr * HM + uo;
            float c = cp32[o], h;
            lstm_cell(ip, fp, gp, op, c, h);
            cp32[o] = c;
            HPw[o]  = (_Float16)h;
        }
        gsync(bar);
    }

    // ================= body LSTM: 8 steps, batch 1 (pad 16) =================
    const _Float16* HPf = HP;  // final para h in buffer 0
#pragma unroll 1
    for (int t = 0; t < 8; ++t) {
        const _Float16* HBr = HB + (size_t)(t & 1) * HM;
        _Float16*       HBw = HB + (size_t)((t + 1) & 1) * HM;
        f32x4 acc = {0.f,0.f,0.f,0.f};
#pragma unroll 4
        for (int k = 0; k < 16; ++k) {
            const int kt = wv * 16 + k;
            const int kk = kt * 32 + krow * 8;
            half8 b, a = h8z();
            if (kk < 1024) {
                b = *reinterpret_cast<const half8*>(bWih + (size_t)grow * HM + kk);
                if (l15 == 0) a = *reinterpret_cast<const half8*>(HPf + (size_t)t * HM + kk);
            } else {
                b = *reinterpret_cast<const half8*>(bWhh + (size_t)grow * HM + (kk - 1024));
                if (l15 == 0) a = *reinterpret_cast<const half8*>(HBr + (kk - 1024));
            }
            acc = __builtin_amdgcn_mfma_f32_16x16x32_f16(a, b, acc, 0, 0, 0);
        }
        lds[wv][krow * 4 + 0][l15] = acc[0];
        lds[wv][krow * 4 + 1][l15] = acc[1];
        lds[wv][krow * 4 + 2][l15] = acc[2];
        lds[wv][krow * 4 + 3][l15] = acc[3];
        __syncthreads();
        if (wv == 0 && rr == 0) {   // lanes 0..3
            float ip = lds[0][0][0+mm]+lds[1][0][0+mm]+lds[2][0][0+mm]+lds[3][0][0+mm] + bbi;
            float fp = lds[0][0][4+mm]+lds[1][0][4+mm]+lds[2][0][4+mm]+lds[3][0][4+mm] + bbf;
            float gp = lds[0][0][8+mm]+lds[1][0][8+mm]+lds[2][0][8+mm]+lds[3][0][8+mm] + bbg;
            float op = lds[0][0][12+mm]+lds[1][0][12+mm]+lds[2][0][12+mm]+lds[3][0][12+mm] + bbo;
            float c = cb32[uo], h;
            lstm_cell(ip, fp, gp, op, c, h);
            cb32[uo] = c;
            HBw[uo]  = (_Float16)h;
            if (t == 7) {
                out[uo]        = h;          // h_body
                out[1024 + uo] = rhid[uo];   // r_hidden
            }
        }
        gsync(bar);
    }
}

// ---------------- host ----------------
extern "C" void kernel_launch(void* const* d_in, const int* in_sizes, int n_in,
                              void* d_out, int out_size, void* d_ws, size_t ws_size,
                              hipStream_t stream) {
    const int*   head  = (const int*)d_in[0];
    const int*   body  = (const int*)d_in[1];
    const float* emb   = (const float*)d_in[2];
    const float* sWihF = (const float*)d_in[3];
    const float* sWhhF = (const float*)d_in[4];
    const float* sbih  = (const float*)d_in[5];
    const float* sbhh  = (const float*)d_in[6];
    const float* pWihF = (const float*)d_in[7];
    const float* pWhhF = (const float*)d_in[8];
    const float* pbih  = (const float*)d_in[9];
    const float* pbhh  = (const float*)d_in[10];
    const float* bWihF = (const float*)d_in[11];
    const float* bWhhF = (const float*)d_in[12];
    const float* bbih  = (const float*)d_in[13];
    const float* bbhh  = (const float*)d_in[14];

    char* ws = (char*)d_ws;
    _Float16* sWih16 = (_Float16*)(ws + OFF_SWIH);
    _Float16* sWhh16 = (_Float16*)(ws + OFF_SWHH);
    _Float16* pWih16 = (_Float16*)(ws + OFF_PWIH);
    _Float16* pWhh16 = (_Float16*)(ws + OFF_PWHH);
    _Float16* bWih16 = (_Float16*)(ws + OFF_BWIH);
    _Float16* bWhh16 = (_Float16*)(ws + OFF_BWHH);
    float*    sbp    = (float*)(ws + OFF_SB);
    float*    pbp    = (float*)(ws + OFF_PB);
    float*    bbp    = (float*)(ws + OFF_BB);
    _Float16* X16    = (_Float16*)(ws + OFF_X16);
    _Float16* Hp     = (_Float16*)(ws + OFF_H);
    float*    c32p   = (float*)(ws + OFF_C32);
    _Float16* HPp    = (_Float16*)(ws + OFF_HP);
    float*    cp32p  = (float*)(ws + OFF_CP);
    _Float16* HBp    = (_Float16*)(ws + OFF_HB);
    float*    cb32p  = (float*)(ws + OFF_CB);
    float*    rhidp  = (float*)(ws + OFF_RH);
    unsigned* barp   = (unsigned*)(ws + OFF_BAR);
    float*    outp   = (float*)d_out;

    hipMemsetAsync(ws + OFF_STATE, 0, STATE_BYTES, stream);
    k_cvt<<<512, 256, 0, stream>>>(sWihF, sWih16, 4096 * 512);
    k_cvt<<<1024, 256, 0, stream>>>(sWhhF, sWhh16, 4096 * 1024);
    k_cvt<<<1024, 256, 0, stream>>>(pWihF, pWih16, 4096 * 1024);
    k_cvt<<<1024, 256, 0, stream>>>(pWhhF, pWhh16, 4096 * 1024);
    k_cvt<<<1024, 256, 0, stream>>>(bWihF, bWih16, 4096 * 1024);
    k_cvt<<<1024, 256, 0, stream>>>(bWhhF, bWhh16, 4096 * 1024);
    k_bias<<<16, 256, 0, stream>>>(sbih, sbhh, pbih, pbhh, bbih, bbhh, sbp, pbp, bbp);
    k_gather<<<2048, 256, 0, stream>>>(head, body, emb, X16);

    void* args[] = { &sWih16, &sWhh16, &pWih16, &pWhh16, &bWih16, &bWhh16,
                     &sbp, &pbp, &bbp, &X16,
                     &Hp, &c32p, &HPp, &cp32p, &HBp, &cb32p,
                     &rhidp, &outp, &barp };
    hipError_t err = hipLaunchCooperativeKernel(reinterpret_cast<void*>(k_main),
                                                dim3(NBLK), dim3(NTHR), args, 0, stream);
    if (err != hipSuccess) {
        // 256 blocks on 256 CUs are co-resident in practice; best-effort fallback.
        k_main<<<NBLK, NTHR, 0, stream>>>(sWih16, sWhh16, pWih16, pWhh16, bWih16, bWhh16,
                                          sbp, pbp, bbp, X16,
                                          Hp, c32p, HPp, cp32p, HBp, cb32p,
                                          rhidp, outp, barp);
    }
}

// Round 5
// 1953.231 us; speedup vs baseline: 3.1957x; 3.1957x over previous
//
#include <hip/hip_runtime.h>

typedef _Float16 half8 __attribute__((ext_vector_type(8)));
typedef float f32x4 __attribute__((ext_vector_type(4)));

#define NBLK 256
#define NTHR 512
#define VD   512
#define HM   1024
#define MPAD 144
#define BSENT 129

// ---------------- workspace layout (total ~56.5 MB) ----------------
static constexpr size_t SZ_SWIH = (size_t)4096 * 512 * 2;
static constexpr size_t SZ_W1K  = (size_t)4096 * 1024 * 2;
static constexpr size_t OFF_SWIH = 0;
static constexpr size_t OFF_SWHH = OFF_SWIH + SZ_SWIH;
static constexpr size_t OFF_PWIH = OFF_SWHH + SZ_W1K;
static constexpr size_t OFF_PWHH = OFF_PWIH + SZ_W1K;
static constexpr size_t OFF_BWIH = OFF_PWHH + SZ_W1K;
static constexpr size_t OFF_BWHH = OFF_BWIH + SZ_W1K;
static constexpr size_t OFF_SB   = OFF_BWHH + SZ_W1K;
static constexpr size_t OFF_PB   = OFF_SB + (size_t)4096 * 4;
static constexpr size_t OFF_BB   = OFF_PB + (size_t)4096 * 4;
static constexpr size_t OFF_X16  = OFF_BB + (size_t)4096 * 4;
static constexpr size_t SZ_X16   = (size_t)64 * MPAD * VD * 2;
static constexpr size_t OFF_STATE = OFF_X16 + SZ_X16;
static constexpr size_t OFF_H    = OFF_STATE;               // [2][144][1024] f16
static constexpr size_t SZ_H     = (size_t)2 * MPAD * HM * 2;
static constexpr size_t OFF_HP   = OFF_H + SZ_H;            // [17][8][1024] f16
static constexpr size_t SZ_HP    = (size_t)17 * 8 * HM * 2;
static constexpr size_t OFF_HB   = OFF_HP + SZ_HP;          // [9][1024] f16
static constexpr size_t SZ_HB    = (size_t)9 * HM * 2;
static constexpr size_t OFF_BAR  = OFF_HB + SZ_HB;          // barrier counters
static constexpr size_t STATE_BYTES = (OFF_BAR + 4096) - OFF_STATE;

// ---------------- helpers ----------------
__device__ __forceinline__ half8 h8z() {
    half8 z = {(_Float16)0,(_Float16)0,(_Float16)0,(_Float16)0,
               (_Float16)0,(_Float16)0,(_Float16)0,(_Float16)0};
    return z;
}

__device__ __forceinline__ half8 ld8(const _Float16* p) {
    return *reinterpret_cast<const half8*>(p);
}

__device__ __forceinline__ void lstm_cell(float ip, float fp, float gp, float op,
                                          float& c, float& h) {
    float ig = 1.0f / (1.0f + expf(-ip));
    float fg = 1.0f / (1.0f + expf(-fp));
    float og = 1.0f / (1.0f + expf(-op));
    float gv = tanhf(gp);
    c = fg * c + ig * gv;
    h = og * tanhf(c);
}

// Grid barrier using the r1-PROVEN __threadfence() machinery (waitcnt + buffer_wbl2
// + waitcnt + buffer_inv), but executed by thread 0's wave ONLY (cache-wide ops:
// one wbl2 flushes the whole XCD L2 incl. all sibling waves' stores, which the
// entry __syncthreads already drained to L2; one inv covers the CU L1 + XCD L2).
// Physical-completion argument: the fence's waitcnt makes the wbl2 COMPLETE before
// the arrival add issues, so arrival-visible => data at L3. Gen visible => all 256
// blocks' wbl2 complete => post-spin fence (inv) + plain loads read fresh data.
// Counters are monotone (round-numbered): 16 sub-counters -> master -> gen.
__device__ __forceinline__ void gsync(unsigned* bar, int round) {
    __syncthreads();                       // all waves' stores vmcnt-drained (to L2)
    if (threadIdx.x == 0) {
        __threadfence();                   // RELEASE: flush XCD L2 -> L3, completed
        const unsigned target = (unsigned)(round * 16 + 15);
        unsigned a = __hip_atomic_fetch_add(&bar[(blockIdx.x & 15) * 32], 1u,
                                            __ATOMIC_RELAXED, __HIP_MEMORY_SCOPE_AGENT);
        if (a == target) {
            unsigned m = __hip_atomic_fetch_add(&bar[512], 1u,
                                                __ATOMIC_RELAXED, __HIP_MEMORY_SCOPE_AGENT);
            if (m == target) {
                __hip_atomic_store(&bar[544], (unsigned)(round + 1),
                                   __ATOMIC_RELAXED, __HIP_MEMORY_SCOPE_AGENT);
            }
        }
        while (__hip_atomic_load(&bar[544], __ATOMIC_RELAXED,
                                 __HIP_MEMORY_SCOPE_AGENT) < (unsigned)(round + 1)) {
            __builtin_amdgcn_s_sleep(2);
        }
        __threadfence();                   // ACQUIRE: inv L1/L2 so plain loads refetch
    }
    __syncthreads();
}

// ---------------- prep kernels ----------------
__global__ void k_cvt(const float* __restrict__ s, _Float16* __restrict__ d, int n) {
    for (int i = blockIdx.x * blockDim.x + threadIdx.x; i < n; i += gridDim.x * blockDim.x)
        d[i] = (_Float16)s[i];
}

__global__ void k_bias(const float* a1, const float* a2, const float* b1, const float* b2,
                       const float* c1, const float* c2,
                       float* sb, float* pb, float* bb) {
    int i = blockIdx.x * blockDim.x + threadIdx.x;
    if (i < 4096) {
        sb[i] = a1[i] + a2[i];
        pb[i] = b1[i] + b2[i];
        bb[i] = c1[i] + c2[i];
    }
}

// X16[t][row][d]; row 0 = headline, rows 1..128 = body sentences, 129..143 zero pad
__global__ void k_gather(const int* __restrict__ head, const int* __restrict__ body,
                         const float* __restrict__ emb, _Float16* __restrict__ X16) {
    const int total = 64 * MPAD * VD;
    for (int idx = blockIdx.x * blockDim.x + threadIdx.x; idx < total;
         idx += gridDim.x * blockDim.x) {
        int d   = idx & (VD - 1);
        int rt  = idx >> 9;
        int row = rt % MPAD;
        int t   = rt / MPAD;
        float v = 0.0f;
        if (row == 0)         v = emb[(size_t)head[t] * VD + d];
        else if (row < BSENT) v = emb[(size_t)body[(row - 1) * 64 + t] * VD + d];
        X16[idx] = (_Float16)v;
    }
}

// ---------------- main persistent kernel ----------------
// 256 blocks x 512 thr (8 waves). Block owns 4 hidden units (16 gate cols).
// ALL weights live in registers (96 VGPR sentence stage, 32 para/body), so the
// per-step L2 invalidate only refetches X/H (~0.5 MB/XCD/step from L3), not the
// 12.6 MB weight set (r1's 263 MB/step refetch).
// Sentence: 9 row-tiles of 16; waves g=wv&3 own tiles {g, g+4, (g==0: 8)};
// K(1536) split 2-way across kh=wv>>2; epilogue reduces the two K-half partials.
extern "C" __global__ void __launch_bounds__(NTHR, 2)
k_main(const _Float16* __restrict__ sWih, const _Float16* __restrict__ sWhh,
       const _Float16* __restrict__ pWih, const _Float16* __restrict__ pWhh,
       const _Float16* __restrict__ bWih, const _Float16* __restrict__ bWhh,
       const float* __restrict__ sb, const float* __restrict__ pb, const float* __restrict__ bb,
       const _Float16* __restrict__ X16,
       _Float16* H, _Float16* HP, _Float16* HB,
       float* out, unsigned* bar)
{
    __shared__ float lds[8][3][16][17];

    const int tid  = threadIdx.x;
    const int lane = tid & 63;
    const int wv   = tid >> 6;        // 0..7
    const int g    = wv & 3;
    const int kh   = wv >> 2;         // K-half
    const int l15  = lane & 15;
    const int krow = lane >> 4;       // 0..3
    const int rr   = lane >> 2;       // epilogue row 0..15
    const int mm   = lane & 3;        // epilogue col 0..3
    const int ubase = blockIdx.x * 4;
    const int uo    = ubase + mm;
    const int grow  = (l15 >> 2) * HM + ubase + (l15 & 3);  // weight row for B col l15

    const float sbi = sb[uo], sbf = sb[1024 + uo], sbg = sb[2048 + uo], sbo = sb[3072 + uo];
    const float pbi = pb[uo], pbf = pb[1024 + uo], pbg = pb[2048 + uo], pbo = pb[3072 + uo];
    const float bbi = bb[uo], bbf = bb[1024 + uo], bbg = bb[2048 + uo], bbo = bb[3072 + uo];

    const int rA0 = g * 16 + l15;     // tile g
    const int rA1 = rA0 + 64;         // tile g+4
    const int rA2 = 128 + l15;        // tile 8 (g==0 waves)

    float c_main = 0.f, c_t8 = 0.f, c_para = 0.f, c_body = 0.f, rhid_reg = 0.f;
    int round = 0;

    // ---- preload sentence-stage weights into registers (96 VGPR / wave) ----
    half8 wS[24];
    if (kh == 0) {
#pragma unroll
        for (int kt = 0; kt < 16; ++kt)
            wS[kt] = ld8(sWih + (size_t)grow * VD + kt * 32 + krow * 8);
#pragma unroll
        for (int kt = 0; kt < 8; ++kt)
            wS[16 + kt] = ld8(sWhh + (size_t)grow * HM + kt * 32 + krow * 8);
    } else {
#pragma unroll
        for (int kt = 0; kt < 24; ++kt)
            wS[kt] = ld8(sWhh + (size_t)grow * HM + (8 + kt) * 32 + krow * 8);
    }

    // ================= sentence LSTM: 64 steps, batch 129 (pad 144) =================
#pragma unroll 1
    for (int t = 0; t < 64; ++t) {
        const _Float16* Xt = X16 + (size_t)t * MPAD * VD;
        const _Float16* Hr = H + (size_t)(t & 1) * MPAD * HM;
        _Float16*       Hw = H + (size_t)((t + 1) & 1) * MPAD * HM;

        f32x4 a0 = {0.f,0.f,0.f,0.f}, a1 = {0.f,0.f,0.f,0.f}, a2 = {0.f,0.f,0.f,0.f};
        if (kh == 0) {
            // x part: K 0..511
#pragma unroll
            for (int kt = 0; kt < 16; ++kt) {
                const int kk = kt * 32 + krow * 8;
                half8 x0 = ld8(Xt + (size_t)rA0 * VD + kk);
                half8 x1 = ld8(Xt + (size_t)rA1 * VD + kk);
                a0 = __builtin_amdgcn_mfma_f32_16x16x32_f16(x0, wS[kt], a0, 0, 0, 0);
                a1 = __builtin_amdgcn_mfma_f32_16x16x32_f16(x1, wS[kt], a1, 0, 0, 0);
                if (g == 0) {
                    half8 x2 = ld8(Xt + (size_t)rA2 * VD + kk);
                    a2 = __builtin_amdgcn_mfma_f32_16x16x32_f16(x2, wS[kt], a2, 0, 0, 0);
                }
            }
            // h part: K-tiles 0..7 (h cols 0..255)
#pragma unroll
            for (int kt = 0; kt < 8; ++kt) {
                const int kk = kt * 32 + krow * 8;
                half8 h0 = ld8(Hr + (size_t)rA0 * HM + kk);
                half8 h1 = ld8(Hr + (size_t)rA1 * HM + kk);
                a0 = __builtin_amdgcn_mfma_f32_16x16x32_f16(h0, wS[16 + kt], a0, 0, 0, 0);
                a1 = __builtin_amdgcn_mfma_f32_16x16x32_f16(h1, wS[16 + kt], a1, 0, 0, 0);
                if (g == 0) {
                    half8 h2 = ld8(Hr + (size_t)rA2 * HM + kk);
                    a2 = __builtin_amdgcn_mfma_f32_16x16x32_f16(h2, wS[16 + kt], a2, 0, 0, 0);
                }
            }
        } else {
            // h part: K-tiles 8..31 (h cols 256..1023)
#pragma unroll
            for (int kt = 0; kt < 24; ++kt) {
                const int kk = (8 + kt) * 32 + krow * 8;
                half8 h0 = ld8(Hr + (size_t)rA0 * HM + kk);
                half8 h1 = ld8(Hr + (size_t)rA1 * HM + kk);
                a0 = __builtin_amdgcn_mfma_f32_16x16x32_f16(h0, wS[kt], a0, 0, 0, 0);
                a1 = __builtin_amdgcn_mfma_f32_16x16x32_f16(h1, wS[kt], a1, 0, 0, 0);
                if (g == 0) {
                    half8 h2 = ld8(Hr + (size_t)rA2 * HM + kk);
                    a2 = __builtin_amdgcn_mfma_f32_16x16x32_f16(h2, wS[kt], a2, 0, 0, 0);
                }
            }
        }
        // stash K-half partials
#pragma unroll
        for (int q = 0; q < 4; ++q) {
            lds[wv][0][krow * 4 + q][l15] = a0[q];
            lds[wv][1][krow * 4 + q][l15] = a1[q];
        }
        if (g == 0) {
#pragma unroll
            for (int q = 0; q < 4; ++q) lds[wv][2][krow * 4 + q][l15] = a2[q];
        }
        __syncthreads();
        // epilogue: wave T reduces the two K-half partials of tile T
        {
            const int T  = wv;
            const int wA = (T < 4) ? T     : T - 4;
            const int wB = (T < 4) ? T + 4 : T;
            const int jj = (T < 4) ? 0 : 1;
            const int rowg = T * 16 + rr;
            if (rowg < BSENT) {
                float ip = lds[wA][jj][rr][ 0 + mm] + lds[wB][jj][rr][ 0 + mm] + sbi;
                float fp = lds[wA][jj][rr][ 4 + mm] + lds[wB][jj][rr][ 4 + mm] + sbf;
                float gp = lds[wA][jj][rr][ 8 + mm] + lds[wB][jj][rr][ 8 + mm] + sbg;
                float op = lds[wA][jj][rr][12 + mm] + lds[wB][jj][rr][12 + mm] + sbo;
                float h;
                lstm_cell(ip, fp, gp, op, c_main, h);
                if (t == 63 && wv == 0 && rr == 0) rhid_reg = h;
                Hw[(size_t)rowg * HM + uo] = (_Float16)h;
            }
        }
        if (wv == 0) {   // tile 8: only row 128 valid
            const int rowg = 128 + rr;
            if (rowg < BSENT) {
                float ip = lds[0][2][rr][ 0 + mm] + lds[4][2][rr][ 0 + mm] + sbi;
                float fp = lds[0][2][rr][ 4 + mm] + lds[4][2][rr][ 4 + mm] + sbf;
                float gp = lds[0][2][rr][ 8 + mm] + lds[4][2][rr][ 8 + mm] + sbg;
                float op = lds[0][2][rr][12 + mm] + lds[4][2][rr][12 + mm] + sbo;
                float h;
                lstm_cell(ip, fp, gp, op, c_t8, h);
                Hw[(size_t)rowg * HM + uo] = (_Float16)h;
            }
        }
        gsync(bar, round); ++round;
    }

    // ---- preload paragraph-stage weights (32 VGPR / wave; wS is dead now) ----
    half8 wP[8];
    if (wv < 4) {
#pragma unroll
        for (int k = 0; k < 8; ++k)
            wP[k] = ld8(pWih + (size_t)grow * HM + (wv * 8 + k) * 32 + krow * 8);
    } else {
#pragma unroll
        for (int k = 0; k < 8; ++k)
            wP[k] = ld8(pWhh + (size_t)grow * HM + ((wv - 4) * 8 + k) * 32 + krow * 8);
    }

    // ================= paragraph LSTM: 16 steps, batch 8 (pad 16) =================
    const _Float16* Hs = H;   // sentence-final h landed in buffer 0
#pragma unroll 1
    for (int s = 0; s < 16; ++s) {
        const _Float16* HPr = HP + (size_t)s * 8 * HM;
        _Float16*       HPw = HP + (size_t)(s + 1) * 8 * HM;
        f32x4 acc = {0.f,0.f,0.f,0.f};
        if (wv < 4) {
            const int rs = 1 + l15 * 16 + s;                  // sent_h[p=l15][s]
#pragma unroll
            for (int k = 0; k < 8; ++k) {
                const int kk = (wv * 8 + k) * 32 + krow * 8;
                half8 a = h8z();
                if (l15 < 8) a = ld8(Hs + (size_t)rs * HM + kk);
                acc = __builtin_amdgcn_mfma_f32_16x16x32_f16(a, wP[k], acc, 0, 0, 0);
            }
        } else {
#pragma unroll
            for (int k = 0; k < 8; ++k) {
                const int kk = ((wv - 4) * 8 + k) * 32 + krow * 8;
                half8 a = h8z();
                if (l15 < 8) a = ld8(HPr + (size_t)l15 * HM + kk);
                acc = __builtin_amdgcn_mfma_f32_16x16x32_f16(a, wP[k], acc, 0, 0, 0);
            }
        }
#pragma unroll
        for (int q = 0; q < 4; ++q) lds[wv][0][krow * 4 + q][l15] = acc[q];
        __syncthreads();
        if (wv == 0 && rr < 8) {
            float ip = pbi, fp = pbf, gp = pbg, op = pbo;
#pragma unroll
            for (int w = 0; w < 8; ++w) {
                ip += lds[w][0][rr][ 0 + mm];
                fp += lds[w][0][rr][ 4 + mm];
                gp += lds[w][0][rr][ 8 + mm];
                op += lds[w][0][rr][12 + mm];
            }
            float h;
            lstm_cell(ip, fp, gp, op, c_para, h);
            HPw[(size_t)rr * HM + uo] = (_Float16)h;
        }
        gsync(bar, round); ++round;
    }

    // ---- preload body-stage weights ----
    half8 wQ[8];
    if (wv < 4) {
#pragma unroll
        for (int k = 0; k < 8; ++k)
            wQ[k] = ld8(bWih + (size_t)grow * HM + (wv * 8 + k) * 32 + krow * 8);
    } else {
#pragma unroll
        for (int k = 0; k < 8; ++k)
            wQ[k] = ld8(bWhh + (size_t)grow * HM + ((wv - 4) * 8 + k) * 32 + krow * 8);
    }

    // ================= body LSTM: 8 steps, batch 1 =================
    const _Float16* HPf = HP + (size_t)16 * 8 * HM;   // para-final h
#pragma unroll 1
    for (int t = 0; t < 8; ++t) {
        const _Float16* HBr = HB + (size_t)t * HM;
        _Float16*       HBw = HB + (size_t)(t + 1) * HM;
        f32x4 acc = {0.f,0.f,0.f,0.f};
        if (wv < 4) {
#pragma unroll
            for (int k = 0; k < 8; ++k) {
                const int kk = (wv * 8 + k) * 32 + krow * 8;
                half8 a = h8z();
                if (l15 == 0) a = ld8(HPf + (size_t)t * HM + kk);
                acc = __builtin_amdgcn_mfma_f32_16x16x32_f16(a, wQ[k], acc, 0, 0, 0);
            }
        } else {
#pragma unroll
            for (int k = 0; k < 8; ++k) {
                const int kk = ((wv - 4) * 8 + k) * 32 + krow * 8;
                half8 a = h8z();
                if (l15 == 0) a = ld8(HBr + kk);
                acc = __builtin_amdgcn_mfma_f32_16x16x32_f16(a, wQ[k], acc, 0, 0, 0);
            }
        }
#pragma unroll
        for (int q = 0; q < 4; ++q) lds[wv][0][krow * 4 + q][l15] = acc[q];
        __syncthreads();
        if (wv == 0 && rr == 0) {   // lanes 0..3
            float ip = bbi, fp = bbf, gp = bbg, op = bbo;
#pragma unroll
            for (int w = 0; w < 8; ++w) {
                ip += lds[w][0][0][ 0 + mm];
                fp += lds[w][0][0][ 4 + mm];
                gp += lds[w][0][0][ 8 + mm];
                op += lds[w][0][0][12 + mm];
            }
            float h;
            lstm_cell(ip, fp, gp, op, c_body, h);
            HBw[uo] = (_Float16)h;
            if (t == 7) {
                out[uo]        = h;          // h_body
                out[1024 + uo] = rhid_reg;   // r_hidden
            }
        }
        gsync(bar, round); ++round;
    }
}

// ---------------- host ----------------
extern "C" void kernel_launch(void* const* d_in, const int* in_sizes, int n_in,
                              void* d_out, int out_size, void* d_ws, size_t ws_size,
                              hipStream_t stream) {
    const int*   head  = (const int*)d_in[0];
    const int*   body  = (const int*)d_in[1];
    const float* emb   = (const float*)d_in[2];
    const float* sWihF = (const float*)d_in[3];
    const float* sWhhF = (const float*)d_in[4];
    const float* sbih  = (const float*)d_in[5];
    const float* sbhh  = (const float*)d_in[6];
    const float* pWihF = (const float*)d_in[7];
    const float* pWhhF = (const float*)d_in[8];
    const float* pbih  = (const float*)d_in[9];
    const float* pbhh  = (const float*)d_in[10];
    const float* bWihF = (const float*)d_in[11];
    const float* bWhhF = (const float*)d_in[12];
    const float* bbih  = (const float*)d_in[13];
    const float* bbhh  = (const float*)d_in[14];

    char* ws = (char*)d_ws;
    _Float16* sWih16 = (_Float16*)(ws + OFF_SWIH);
    _Float16* sWhh16 = (_Float16*)(ws + OFF_SWHH);
    _Float16* pWih16 = (_Float16*)(ws + OFF_PWIH);
    _Float16* pWhh16 = (_Float16*)(ws + OFF_PWHH);
    _Float16* bWih16 = (_Float16*)(ws + OFF_BWIH);
    _Float16* bWhh16 = (_Float16*)(ws + OFF_BWHH);
    float*    sbp    = (float*)(ws + OFF_SB);
    float*    pbp    = (float*)(ws + OFF_PB);
    float*    bbp    = (float*)(ws + OFF_BB);
    _Float16* X16    = (_Float16*)(ws + OFF_X16);
    _Float16* Hp     = (_Float16*)(ws + OFF_H);
    _Float16* HPp    = (_Float16*)(ws + OFF_HP);
    _Float16* HBp    = (_Float16*)(ws + OFF_HB);
    unsigned* barp   = (unsigned*)(ws + OFF_BAR);
    float*    outp   = (float*)d_out;

    hipMemsetAsync(ws + OFF_STATE, 0, STATE_BYTES, stream);
    k_cvt<<<512, 256, 0, stream>>>(sWihF, sWih16, 4096 * 512);
    k_cvt<<<1024, 256, 0, stream>>>(sWhhF, sWhh16, 4096 * 1024);
    k_cvt<<<1024, 256, 0, stream>>>(pWihF, pWih16, 4096 * 1024);
    k_cvt<<<1024, 256, 0, stream>>>(pWhhF, pWhh16, 4096 * 1024);
    k_cvt<<<1024, 256, 0, stream>>>(bWihF, bWih16, 4096 * 1024);
    k_cvt<<<1024, 256, 0, stream>>>(bWhhF, bWhh16, 4096 * 1024);
    k_bias<<<16, 256, 0, stream>>>(sbih, sbhh, pbih, pbhh, bbih, bbhh, sbp, pbp, bbp);
    k_gather<<<2048, 256, 0, stream>>>(head, body, emb, X16);

    void* args[] = { &sWih16, &sWhh16, &pWih16, &pWhh16, &bWih16, &bWhh16,
                     &sbp, &pbp, &bbp, &X16,
                     &Hp, &HPp, &HBp, &outp, &barp };
    hipError_t err = hipLaunchCooperativeKernel(reinterpret_cast<void*>(k_main),
                                                dim3(NBLK), dim3(NTHR), args, 0, stream);
    if (err != hipSuccess) {
        // 256 blocks x 512 thr = 8 waves/CU on 256 CUs are co-resident; best-effort fallback.
        k_main<<<NBLK, NTHR, 0, stream>>>(sWih16, sWhh16, pWih16, pWhh16, bWih16, bWhh16,
                                          sbp, pbp, bbp, X16,
                                          Hp, HPp, HBp, outp, barp);
    }
}

// Round 6
// 1368.018 us; speedup vs baseline: 4.5628x; 1.4278x over previous
//
#include <hip/hip_runtime.h>

typedef _Float16 half8 __attribute__((ext_vector_type(8)));
typedef float f32x4 __attribute__((ext_vector_type(4)));

#define NBLK 256
#define NTHR 512
#define VD   512
#define HM   1024
#define MPAD 144
#define BSENT 129

// HW_REG_XCC_ID (id=20, offset=0, size=4) -> imm = 20 | (0<<6) | (3<<11)
#define XCC_ID_IMM 6164

// ---------------- workspace layout (total ~56.5 MB) ----------------
static constexpr size_t SZ_SWIH = (size_t)4096 * 512 * 2;
static constexpr size_t SZ_W1K  = (size_t)4096 * 1024 * 2;
static constexpr size_t OFF_SWIH = 0;
static constexpr size_t OFF_SWHH = OFF_SWIH + SZ_SWIH;
static constexpr size_t OFF_PWIH = OFF_SWHH + SZ_W1K;
static constexpr size_t OFF_PWHH = OFF_PWIH + SZ_W1K;
static constexpr size_t OFF_BWIH = OFF_PWHH + SZ_W1K;
static constexpr size_t OFF_BWHH = OFF_BWIH + SZ_W1K;
static constexpr size_t OFF_SB   = OFF_BWHH + SZ_W1K;
static constexpr size_t OFF_PB   = OFF_SB + (size_t)4096 * 4;
static constexpr size_t OFF_BB   = OFF_PB + (size_t)4096 * 4;
static constexpr size_t OFF_X16  = OFF_BB + (size_t)4096 * 4;
static constexpr size_t SZ_X16   = (size_t)64 * MPAD * VD * 2;
static constexpr size_t OFF_STATE = OFF_X16 + SZ_X16;
static constexpr size_t OFF_H    = OFF_STATE;               // [2][144][1024] f16
static constexpr size_t SZ_H     = (size_t)2 * MPAD * HM * 2;
static constexpr size_t OFF_HP   = OFF_H + SZ_H;            // [17][8][1024] f16
static constexpr size_t SZ_HP    = (size_t)17 * 8 * HM * 2;
static constexpr size_t OFF_HB   = OFF_HP + SZ_HP;          // [9][1024] f16
static constexpr size_t SZ_HB    = (size_t)9 * HM * 2;
static constexpr size_t OFF_BAR  = OFF_HB + SZ_HB;          // barrier counters (4 KB)
static constexpr size_t STATE_BYTES = (OFF_BAR + 4096) - OFF_STATE;

// bar[] layout (uint32 indices): cen[g]=bar[g*16] (g<16); census barrier:
// csub[i]=bar[256+i*16], cmaster=bar[512], cgen=bar[520];
// per-step: loc[g]=bar[528+g*16], master=bar[800], gen=bar[832].

// ---------------- helpers ----------------
__device__ __forceinline__ half8 h8z() {
    half8 z = {(_Float16)0,(_Float16)0,(_Float16)0,(_Float16)0,
               (_Float16)0,(_Float16)0,(_Float16)0,(_Float16)0};
    return z;
}

__device__ __forceinline__ half8 ld8(const _Float16* p) {
    return *reinterpret_cast<const half8*>(p);
}

__device__ __forceinline__ void lstm_cell(float ip, float fp, float gp, float op,
                                          float& c, float& h) {
    float ig = 1.0f / (1.0f + expf(-ip));
    float fg = 1.0f / (1.0f + expf(-fp));
    float og = 1.0f / (1.0f + expf(-op));
    float gv = tanhf(gp);
    c = fg * c + ig * gv;
    h = og * tanhf(c);
}

// One-shot census barrier: r5's PROVEN full-threadfence barrier, own counters.
__device__ __forceinline__ void gsync_census(unsigned* bar) {
    __syncthreads();
    if (threadIdx.x == 0) {
        __threadfence();
        unsigned a = __hip_atomic_fetch_add(&bar[256 + (blockIdx.x & 15) * 16], 1u,
                                            __ATOMIC_RELAXED, __HIP_MEMORY_SCOPE_AGENT);
        if (a == 15u) {
            unsigned m = __hip_atomic_fetch_add(&bar[512], 1u,
                                                __ATOMIC_RELAXED, __HIP_MEMORY_SCOPE_AGENT);
            if (m == 15u)
                __hip_atomic_store(&bar[520], 1u,
                                   __ATOMIC_RELAXED, __HIP_MEMORY_SCOPE_AGENT);
        }
        while (__hip_atomic_load(&bar[520], __ATOMIC_RELAXED,
                                 __HIP_MEMORY_SCOPE_AGENT) < 1u)
            __builtin_amdgcn_s_sleep(2);
        __threadfence();
    }
    __syncthreads();
}

// Per-step barrier, designated-flusher edition.
// Entry __syncthreads drains every wave's plain h-stores into the local L2
// (vmcnt=0 => store completed in L2). Last LOCAL arriver of this XCD's counter
// executes the r5-PROVEN __threadfence() (waitcnt+wbl2+waitcnt+inv: flushes the
// whole XCD L2 -> L3, completed), then signals the master. gen visible => all
// nE XCDs flushed+invalidated. Every block then invalidates its own CU L1
// (buffer_inv sc0, parallel per-CU, no L2 serialization) so plain loads refetch
// through the (fresh) L2. Counters monotone, no resets.
__device__ __forceinline__ void gsync2(unsigned* bar, int round,
                                       unsigned g, unsigned cnt, unsigned nE) {
    __syncthreads();
    if (threadIdx.x == 0) {
        unsigned a = __hip_atomic_fetch_add(&bar[528 + g * 16], 1u,
                                            __ATOMIC_RELAXED, __HIP_MEMORY_SCOPE_AGENT);
        if (a == (unsigned)(round + 1) * cnt - 1u) {      // designated for this XCD
            __threadfence();
            unsigned m = __hip_atomic_fetch_add(&bar[800], 1u,
                                                __ATOMIC_RELAXED, __HIP_MEMORY_SCOPE_AGENT);
            if (m == (unsigned)(round + 1) * nE - 1u) {
                __hip_atomic_store(&bar[832], (unsigned)(round + 1),
                                   __ATOMIC_RELAXED, __HIP_MEMORY_SCOPE_AGENT);
            }
        }
        while (__hip_atomic_load(&bar[832], __ATOMIC_RELAXED,
                                 __HIP_MEMORY_SCOPE_AGENT) < (unsigned)(round + 1))
            __builtin_amdgcn_s_sleep(2);
        // per-CU L1 invalidate; completion via vmcnt before exiting
        asm volatile("buffer_inv sc0\n\ts_waitcnt vmcnt(0)" ::: "memory");
    }
    __syncthreads();
}

// ---------------- prep kernels ----------------
__global__ void k_cvt(const float* __restrict__ s, _Float16* __restrict__ d, int n) {
    for (int i = blockIdx.x * blockDim.x + threadIdx.x; i < n; i += gridDim.x * blockDim.x)
        d[i] = (_Float16)s[i];
}

__global__ void k_bias(const float* a1, const float* a2, const float* b1, const float* b2,
                       const float* c1, const float* c2,
                       float* sb, float* pb, float* bb) {
    int i = blockIdx.x * blockDim.x + threadIdx.x;
    if (i < 4096) {
        sb[i] = a1[i] + a2[i];
        pb[i] = b1[i] + b2[i];
        bb[i] = c1[i] + c2[i];
    }
}

// X16[t][row][d]; row 0 = headline, rows 1..128 = body sentences, 129..143 zero pad
__global__ void k_gather(const int* __restrict__ head, const int* __restrict__ body,
                         const float* __restrict__ emb, _Float16* __restrict__ X16) {
    const int total = 64 * MPAD * VD;
    for (int idx = blockIdx.x * blockDim.x + threadIdx.x; idx < total;
         idx += gridDim.x * blockDim.x) {
        int d   = idx & (VD - 1);
        int rt  = idx >> 9;
        int row = rt % MPAD;
        int t   = rt / MPAD;
        float v = 0.0f;
        if (row == 0)         v = emb[(size_t)head[t] * VD + d];
        else if (row < BSENT) v = emb[(size_t)body[(row - 1) * 64 + t] * VD + d];
        X16[idx] = (_Float16)v;
    }
}

// ---------------- main persistent kernel ----------------
// 256 blocks x 512 thr (8 waves). Block owns 4 hidden units (16 gate cols).
// Weights live in LDS (64 KB wfrag, staged once per stage) — immune to the
// per-step L2 invalidate, so post-inv refetch is only X/H (~0.5 MB/XCD/step, L3).
// Sentence: 9 row-tiles of 16; waves g=wv&3 own tiles {g, g+4, (g==0: 8)};
// K(1536) split 2-way across kh=wv>>2; epilogue reduces the two K-half partials.
extern "C" __global__ void __launch_bounds__(NTHR, 2)
k_main(const _Float16* __restrict__ sWih, const _Float16* __restrict__ sWhh,
       const _Float16* __restrict__ pWih, const _Float16* __restrict__ pWhh,
       const _Float16* __restrict__ bWih, const _Float16* __restrict__ bWhh,
       const float* __restrict__ sb, const float* __restrict__ pb, const float* __restrict__ bb,
       const _Float16* __restrict__ X16,
       _Float16* H, _Float16* HP, _Float16* HB,
       float* out, unsigned* bar)
{
    __shared__ float lds[8][3][16][17];
    __shared__ half8 wfrag[4096];     // 64 KB: B-fragments for the current stage

    const int tid  = threadIdx.x;
    const int lane = tid & 63;
    const int wv   = tid >> 6;        // 0..7
    const int g    = wv & 3;
    const int kh   = wv >> 2;         // K-half
    const int l15  = lane & 15;
    const int krow = lane >> 4;       // 0..3
    const int rr   = lane >> 2;       // epilogue row 0..15
    const int mm   = lane & 3;        // epilogue col 0..3
    const int ubase = blockIdx.x * 4;
    const int uo    = ubase + mm;
    const int grow  = (l15 >> 2) * HM + ubase + (l15 & 3);  // weight row for B col l15

    const float sbi = sb[uo], sbf = sb[1024 + uo], sbg = sb[2048 + uo], sbo = sb[3072 + uo];
    const float pbi = pb[uo], pbf = pb[1024 + uo], pbg = pb[2048 + uo], pbo = pb[3072 + uo];
    const float bbi = bb[uo], bbf = bb[1024 + uo], bbg = bb[2048 + uo], bbo = bb[3072 + uo];

    const int rA0 = g * 16 + l15;     // tile g
    const int rA1 = rA0 + 64;         // tile g+4
    const int rA2 = 128 + l15;        // tile 8 (g==0 waves)

    float c_main = 0.f, c_t8 = 0.f, c_para = 0.f, c_body = 0.f, rhid_reg = 0.f;
    int round = 0;

    // ---- census: learn this block's physical XCD and blocks-per-XCD ----
    unsigned myG = 0, myCnt = 0, myNE = 0;
    {
        unsigned xcc = __builtin_amdgcn_s_getreg(XCC_ID_IMM) & 15u;
        if (tid == 0) {
            __hip_atomic_fetch_add(&bar[xcc * 16], 1u,
                                   __ATOMIC_RELAXED, __HIP_MEMORY_SCOPE_AGENT);
        }
        // ---- stage sentence-stage weight fragments into LDS while census settles ----
        // x-part: kt 0..15 -> slot kt ; h-part: kt 0..31 -> slot 16+kt
#pragma unroll
        for (int q = 0; q < 2; ++q) {
            int kt = wv + q * 8;
            wfrag[kt * 64 + lane] = ld8(sWih + (size_t)grow * VD + kt * 32 + krow * 8);
        }
#pragma unroll
        for (int q = 0; q < 4; ++q) {
            int kt = wv + q * 8;
            wfrag[(16 + kt) * 64 + lane] = ld8(sWhh + (size_t)grow * HM + kt * 32 + krow * 8);
        }
        gsync_census(bar);
        if (tid == 0) {
            myG = xcc;
            myCnt = __hip_atomic_load(&bar[xcc * 16], __ATOMIC_RELAXED,
                                      __HIP_MEMORY_SCOPE_AGENT);
            myNE = 0;
            for (int i = 0; i < 16; ++i) {
                unsigned c = __hip_atomic_load(&bar[i * 16], __ATOMIC_RELAXED,
                                               __HIP_MEMORY_SCOPE_AGENT);
                myNE += (c != 0u) ? 1u : 0u;
            }
        }
    }

    // ================= sentence LSTM: 64 steps, batch 129 (pad 144) =================
#pragma unroll 1
    for (int t = 0; t < 64; ++t) {
        const _Float16* Xt = X16 + (size_t)t * MPAD * VD;
        const _Float16* Hr = H + (size_t)(t & 1) * MPAD * HM;
        _Float16*       Hw = H + (size_t)((t + 1) & 1) * MPAD * HM;

        f32x4 a0 = {0.f,0.f,0.f,0.f}, a1 = {0.f,0.f,0.f,0.f}, a2 = {0.f,0.f,0.f,0.f};
        if (kh == 0) {
            // x part: K 0..511 (slots 0..15)
#pragma unroll
            for (int kt = 0; kt < 16; ++kt) {
                const int kk = kt * 32 + krow * 8;
                half8 b  = wfrag[kt * 64 + lane];
                half8 x0 = ld8(Xt + (size_t)rA0 * VD + kk);
                half8 x1 = ld8(Xt + (size_t)rA1 * VD + kk);
                a0 = __builtin_amdgcn_mfma_f32_16x16x32_f16(x0, b, a0, 0, 0, 0);
                a1 = __builtin_amdgcn_mfma_f32_16x16x32_f16(x1, b, a1, 0, 0, 0);
                if (g == 0) {
                    half8 x2 = ld8(Xt + (size_t)rA2 * VD + kk);
                    a2 = __builtin_amdgcn_mfma_f32_16x16x32_f16(x2, b, a2, 0, 0, 0);
                }
            }
            // h part: K-tiles 0..7 (slots 16..23)
#pragma unroll
            for (int kt = 0; kt < 8; ++kt) {
                const int kk = kt * 32 + krow * 8;
                half8 b  = wfrag[(16 + kt) * 64 + lane];
                half8 h0 = ld8(Hr + (size_t)rA0 * HM + kk);
                half8 h1 = ld8(Hr + (size_t)rA1 * HM + kk);
                a0 = __builtin_amdgcn_mfma_f32_16x16x32_f16(h0, b, a0, 0, 0, 0);
                a1 = __builtin_amdgcn_mfma_f32_16x16x32_f16(h1, b, a1, 0, 0, 0);
                if (g == 0) {
                    half8 h2 = ld8(Hr + (size_t)rA2 * HM + kk);
                    a2 = __builtin_amdgcn_mfma_f32_16x16x32_f16(h2, b, a2, 0, 0, 0);
                }
            }
        } else {
            // h part: K-tiles 8..31 (slots 24..47)
#pragma unroll
            for (int kt = 0; kt < 24; ++kt) {
                const int kk = (8 + kt) * 32 + krow * 8;
                half8 b  = wfrag[(24 + kt) * 64 + lane];
                half8 h0 = ld8(Hr + (size_t)rA0 * HM + kk);
                half8 h1 = ld8(Hr + (size_t)rA1 * HM + kk);
                a0 = __builtin_amdgcn_mfma_f32_16x16x32_f16(h0, b, a0, 0, 0, 0);
                a1 = __builtin_amdgcn_mfma_f32_16x16x32_f16(h1, b, a1, 0, 0, 0);
                if (g == 0) {
                    half8 h2 = ld8(Hr + (size_t)rA2 * HM + kk);
                    a2 = __builtin_amdgcn_mfma_f32_16x16x32_f16(h2, b, a2, 0, 0, 0);
                }
            }
        }
        // stash K-half partials
#pragma unroll
        for (int q = 0; q < 4; ++q) {
            lds[wv][0][krow * 4 + q][l15] = a0[q];
            lds[wv][1][krow * 4 + q][l15] = a1[q];
        }
        if (g == 0) {
#pragma unroll
            for (int q = 0; q < 4; ++q) lds[wv][2][krow * 4 + q][l15] = a2[q];
        }
        __syncthreads();
        // epilogue: wave T reduces the two K-half partials of tile T
        {
            const int T  = wv;
            const int wA = (T < 4) ? T     : T - 4;
            const int wB = (T < 4) ? T + 4 : T;
            const int jj = (T < 4) ? 0 : 1;
            const int rowg = T * 16 + rr;
            if (rowg < BSENT) {
                float ip = lds[wA][jj][rr][ 0 + mm] + lds[wB][jj][rr][ 0 + mm] + sbi;
                float fp = lds[wA][jj][rr][ 4 + mm] + lds[wB][jj][rr][ 4 + mm] + sbf;
                float gp = lds[wA][jj][rr][ 8 + mm] + lds[wB][jj][rr][ 8 + mm] + sbg;
                float op = lds[wA][jj][rr][12 + mm] + lds[wB][jj][rr][12 + mm] + sbo;
                float h;
                lstm_cell(ip, fp, gp, op, c_main, h);
                if (t == 63 && wv == 0 && rr == 0) rhid_reg = h;
                Hw[(size_t)rowg * HM + uo] = (_Float16)h;
            }
        }
        if (wv == 0) {   // tile 8: only row 128 valid
            const int rowg = 128 + rr;
            if (rowg < BSENT) {
                float ip = lds[0][2][rr][ 0 + mm] + lds[4][2][rr][ 0 + mm] + sbi;
                float fp = lds[0][2][rr][ 4 + mm] + lds[4][2][rr][ 4 + mm] + sbf;
                float gp = lds[0][2][rr][ 8 + mm] + lds[4][2][rr][ 8 + mm] + sbg;
                float op = lds[0][2][rr][12 + mm] + lds[4][2][rr][12 + mm] + sbo;
                float h;
                lstm_cell(ip, fp, gp, op, c_t8, h);
                Hw[(size_t)rowg * HM + uo] = (_Float16)h;
            }
        }
        gsync2(bar, round, myG, myCnt, myNE); ++round;
    }

    // ---- stage paragraph-stage weights: ih kt0..31 -> slot kt, hh -> slot 32+kt ----
#pragma unroll
    for (int q = 0; q < 4; ++q) {
        int kt = wv + q * 8;
        wfrag[kt * 64 + lane]        = ld8(pWih + (size_t)grow * HM + kt * 32 + krow * 8);
        wfrag[(32 + kt) * 64 + lane] = ld8(pWhh + (size_t)grow * HM + kt * 32 + krow * 8);
    }
    __syncthreads();

    // ================= paragraph LSTM: 16 steps, batch 8 (pad 16) =================
    const _Float16* Hs = H;   // sentence-final h landed in buffer 0
#pragma unroll 1
    for (int s = 0; s < 16; ++s) {
        const _Float16* HPr = HP + (size_t)s * 8 * HM;
        _Float16*       HPw = HP + (size_t)(s + 1) * 8 * HM;
        f32x4 acc = {0.f,0.f,0.f,0.f};
        if (wv < 4) {
            const int rs = 1 + l15 * 16 + s;                  // sent_h[p=l15][s]
#pragma unroll
            for (int k = 0; k < 8; ++k) {
                const int kt = wv * 8 + k;
                const int kk = kt * 32 + krow * 8;
                half8 b = wfrag[kt * 64 + lane];
                half8 a = h8z();
                if (l15 < 8) a = ld8(Hs + (size_t)rs * HM + kk);
                acc = __builtin_amdgcn_mfma_f32_16x16x32_f16(a, b, acc, 0, 0, 0);
            }
        } else {
#pragma unroll
            for (int k = 0; k < 8; ++k) {
                const int kt = (wv - 4) * 8 + k;
                const int kk = kt * 32 + krow * 8;
                half8 b = wfrag[(32 + kt) * 64 + lane];
                half8 a = h8z();
                if (l15 < 8) a = ld8(HPr + (size_t)l15 * HM + kk);
                acc = __builtin_amdgcn_mfma_f32_16x16x32_f16(a, b, acc, 0, 0, 0);
            }
        }
#pragma unroll
        for (int q = 0; q < 4; ++q) lds[wv][0][krow * 4 + q][l15] = acc[q];
        __syncthreads();
        if (wv == 0 && rr < 8) {
            float ip = pbi, fp = pbf, gp = pbg, op = pbo;
#pragma unroll
            for (int w = 0; w < 8; ++w) {
                ip += lds[w][0][rr][ 0 + mm];
                fp += lds[w][0][rr][ 4 + mm];
                gp += lds[w][0][rr][ 8 + mm];
                op += lds[w][0][rr][12 + mm];
            }
            float h;
            lstm_cell(ip, fp, gp, op, c_para, h);
            HPw[(size_t)rr * HM + uo] = (_Float16)h;
        }
        gsync2(bar, round, myG, myCnt, myNE); ++round;
    }

    // ---- stage body-stage weights (same slot scheme) ----
#pragma unroll
    for (int q = 0; q < 4; ++q) {
        int kt = wv + q * 8;
        wfrag[kt * 64 + lane]        = ld8(bWih + (size_t)grow * HM + kt * 32 + krow * 8);
        wfrag[(32 + kt) * 64 + lane] = ld8(bWhh + (size_t)grow * HM + kt * 32 + krow * 8);
    }
    __syncthreads();

    // ================= body LSTM: 8 steps, batch 1 =================
    const _Float16* HPf = HP + (size_t)16 * 8 * HM;   // para-final h
#pragma unroll 1
    for (int t = 0; t < 8; ++t) {
        const _Float16* HBr = HB + (size_t)t * HM;
        _Float16*       HBw = HB + (size_t)(t + 1) * HM;
        f32x4 acc = {0.f,0.f,0.f,0.f};
        if (wv < 4) {
#pragma unroll
            for (int k = 0; k < 8; ++k) {
                const int kt = wv * 8 + k;
                const int kk = kt * 32 + krow * 8;
                half8 b = wfrag[kt * 64 + lane];
                half8 a = h8z();
                if (l15 == 0) a = ld8(HPf + (size_t)t * HM + kk);
                acc = __builtin_amdgcn_mfma_f32_16x16x32_f16(a, b, acc, 0, 0, 0);
            }
        } else {
#pragma unroll
            for (int k = 0; k < 8; ++k) {
                const int kt = (wv - 4) * 8 + k;
                const int kk = kt * 32 + krow * 8;
                half8 b = wfrag[(32 + kt) * 64 + lane];
                half8 a = h8z();
                if (l15 == 0) a = ld8(HBr + kk);
                acc = __builtin_amdgcn_mfma_f32_16x16x32_f16(a, b, acc, 0, 0, 0);
            }
        }
#pragma unroll
        for (int q = 0; q < 4; ++q) lds[wv][0][krow * 4 + q][l15] = acc[q];
        __syncthreads();
        if (wv == 0 && rr == 0) {   // lanes 0..3
            float ip = bbi, fp = bbf, gp = bbg, op = bbo;
#pragma unroll
            for (int w = 0; w < 8; ++w) {
                ip += lds[w][0][0][ 0 + mm];
                fp += lds[w][0][0][ 4 + mm];
                gp += lds[w][0][0][ 8 + mm];
                op += lds[w][0][0][12 + mm];
            }
            float h;
            lstm_cell(ip, fp, gp, op, c_body, h);
            HBw[uo] = (_Float16)h;
            if (t == 7) {
                out[uo]        = h;          // h_body
                out[1024 + uo] = rhid_reg;   // r_hidden
            }
        }
        gsync2(bar, round, myG, myCnt, myNE); ++round;
    }
}

// ---------------- host ----------------
extern "C" void kernel_launch(void* const* d_in, const int* in_sizes, int n_in,
                              void* d_out, int out_size, void* d_ws, size_t ws_size,
                              hipStream_t stream) {
    const int*   head  = (const int*)d_in[0];
    const int*   body  = (const int*)d_in[1];
    const float* emb   = (const float*)d_in[2];
    const float* sWihF = (const float*)d_in[3];
    const float* sWhhF = (const float*)d_in[4];
    const float* sbih  = (const float*)d_in[5];
    const float* sbhh  = (const float*)d_in[6];
    const float* pWihF = (const float*)d_in[7];
    const float* pWhhF = (const float*)d_in[8];
    const float* pbih  = (const float*)d_in[9];
    const float* pbhh  = (const float*)d_in[10];
    const float* bWihF = (const float*)d_in[11];
    const float* bWhhF = (const float*)d_in[12];
    const float* bbih  = (const float*)d_in[13];
    const float* bbhh  = (const float*)d_in[14];

    char* ws = (char*)d_ws;
    _Float16* sWih16 = (_Float16*)(ws + OFF_SWIH);
    _Float16* sWhh16 = (_Float16*)(ws + OFF_SWHH);
    _Float16* pWih16 = (_Float16*)(ws + OFF_PWIH);
    _Float16* pWhh16 = (_Float16*)(ws + OFF_PWHH);
    _Float16* bWih16 = (_Float16*)(ws + OFF_BWIH);
    _Float16* bWhh16 = (_Float16*)(ws + OFF_BWHH);
    float*    sbp    = (float*)(ws + OFF_SB);
    float*    pbp    = (float*)(ws + OFF_PB);
    float*    bbp    = (float*)(ws + OFF_BB);
    _Float16* X16    = (_Float16*)(ws + OFF_X16);
    _Float16* Hp     = (_Float16*)(ws + OFF_H);
    _Float16* HPp    = (_Float16*)(ws + OFF_HP);
    _Float16* HBp    = (_Float16*)(ws + OFF_HB);
    unsigned* barp   = (unsigned*)(ws + OFF_BAR);
    float*    outp   = (float*)d_out;

    hipMemsetAsync(ws + OFF_STATE, 0, STATE_BYTES, stream);
    k_cvt<<<512, 256, 0, stream>>>(sWihF, sWih16, 4096 * 512);
    k_cvt<<<1024, 256, 0, stream>>>(sWhhF, sWhh16, 4096 * 1024);
    k_cvt<<<1024, 256, 0, stream>>>(pWihF, pWih16, 4096 * 1024);
    k_cvt<<<1024, 256, 0, stream>>>(pWhhF, pWhh16, 4096 * 1024);
    k_cvt<<<1024, 256, 0, stream>>>(bWihF, bWih16, 4096 * 1024);
    k_cvt<<<1024, 256, 0, stream>>>(bWhhF, bWhh16, 4096 * 1024);
    k_bias<<<16, 256, 0, stream>>>(sbih, sbhh, pbih, pbhh, bbih, bbhh, sbp, pbp, bbp);
    k_gather<<<2048, 256, 0, stream>>>(head, body, emb, X16);

    void* args[] = { &sWih16, &sWhh16, &pWih16, &pWhh16, &bWih16, &bWhh16,
                     &sbp, &pbp, &bbp, &X16,
                     &Hp, &HPp, &HBp, &outp, &barp };
    hipError_t err = hipLaunchCooperativeKernel(reinterpret_cast<void*>(k_main),
                                                dim3(NBLK), dim3(NTHR), args, 0, stream);
    if (err != hipSuccess) {
        // 256 blocks x 512 thr = 8 waves/CU on 256 CUs are co-resident; best-effort fallback.
        k_main<<<NBLK, NTHR, 0, stream>>>(sWih16, sWhh16, pWih16, pWhh16, bWih16, bWhh16,
                                          sbp, pbp, bbp, X16,
                                          Hp, HPp, HBp, outp, barp);
    }
}